// Round 13
// baseline (452.426 us; speedup 1.0000x reference)
//
#include <hip/hip_runtime.h>
#include <math.h>

typedef unsigned short ushort_t;
typedef unsigned int uint_t;
typedef unsigned long long u64_t;
typedef __bf16 bf16x8_t __attribute__((ext_vector_type(8)));
typedef float f32x4_t __attribute__((ext_vector_type(4)));

static constexpr int NPTS = 1024;
static constexpr int NB = 64;
static constexpr int NPOINTS = NB * NPTS;   // 65536
static constexpr int KNB = 16;

__device__ __forceinline__ ushort_t f2bf(float f) {
    uint_t u = __float_as_uint(f);
    uint_t r = (u + 0x7FFFu + ((u >> 16) & 1u)) >> 16;
    return (ushort_t)r;
}
// pack distance (clamped >=0, 22 bits kept) + batch-local j (10 bits).
__device__ __forceinline__ uint_t packdj(float d, int j) {
    return (__float_as_uint(fmaxf(d, 0.f)) & 0xFFFFFC00u) | (uint_t)j;
}
// single-instruction median: for sorted L[k-1]<=L[k], post-insert
// L'[k] = med3(L[k-1], L[k], c). One VOP3 per step; all steps independent.
__device__ __forceinline__ uint_t med3u(uint_t a, uint_t b, uint_t c) {
    uint_t d;
    asm("v_med3_u32 %0, %1, %2, %3" : "=v"(d) : "v"(a), "v"(b), "v"(c));
    return d;
}
__device__ __forceinline__ void insert16(uint_t* L, uint_t c) {
    #pragma unroll
    for (int k = 15; k > 0; --k)
        L[k] = med3u(L[k - 1], L[k], c);
    L[0] = L[0] < c ? L[0] : c;
}
// Merge two ASCENDING sorted 16-lists, keep the 16 smallest, result ascending.
// t[k] = min(A[k], B[15-k]) is bitonic; 4-stage half-cleaner sorts it.
// 80 compare-exchange vs 272 VALU for 16x insert16. (Verified in-harness r7/r8.)
__device__ __forceinline__ void merge16(uint_t* L, const uint_t* B) {
    uint_t t[16];
    #pragma unroll
    for (int k = 0; k < 16; ++k) t[k] = L[k] < B[15 - k] ? L[k] : B[15 - k];
    #pragma unroll
    for (int j = 8; j >= 1; j >>= 1) {
        #pragma unroll
        for (int k = 0; k < 16; ++k) {
            if ((k & j) == 0) {
                uint_t a = t[k], c = t[k | j];
                t[k] = a < c ? a : c;
                t[k | j] = a < c ? c : a;
            }
        }
    }
    #pragma unroll
    for (int k = 0; k < 16; ++k) L[k] = t[k];
}
// monotone float->uint order transform
__device__ __forceinline__ uint_t f2ord(float f) {
    uint_t u = __float_as_uint(f);
    return (u & 0x80000000u) ? ~u : (u ^ 0x80000000u);
}

// Build hi/lo bf16x8 A-fragments from 8 relu'd floats with v_perm_b32 packing.
// H word q = (bits(g[2q])>>16) | (bits(g[2q+1]) & 0xFFFF0000)  -- one v_perm.
// L uses TRUNCATED low part (bit-identical to the previous shift/or sequence).
__device__ __forceinline__ void pack_hilo8(const float* g, bf16x8_t* Ah, bf16x8_t* Al) {
    union { uint_t w[4]; bf16x8_t v8; } H, L;
    #pragma unroll
    for (int q = 0; q < 4; ++q) {
        float g0 = g[2 * q], g1 = g[2 * q + 1];
        uint_t u0 = __float_as_uint(g0), u1 = __float_as_uint(g1);
        H.w[q] = __builtin_amdgcn_perm(u1, u0, 0x07060302u);
        float d0 = g0 - __uint_as_float(u0 & 0xFFFF0000u);
        float d1 = g1 - __uint_as_float(u1 & 0xFFFF0000u);
        L.w[q] = __builtin_amdgcn_perm(__float_as_uint(d1), __float_as_uint(d0),
                                       0x07060302u);
    }
    *Ah = H.v8; *Al = L.v8;
}

// ---------------- fused weight prep + layer-1 sort-knn ----------------
// blocks 0..95   : mlp w1 frags (24576)
// blocks 96..143 : 3x edge w2 frags (4096 each)
// block  144     : layer-1 uv scalar consts (3072 floats)
// blocks 145..208: 2x uv [wd|wb] frags for layers 2/3 (8192 each)
// blocks 209..240: mlp w2 frags (8192)
// blocks 241..248: mlp w3 frags (2048)
// blocks 249..312: layer-1 knn (C=1): bitonic sort + +/-16 window (1 batch each)
__global__ __launch_bounds__(256) void prep_kernel(const float* __restrict__ mw1,
                                                   const float* __restrict__ c1w2,
                                                   const float* __restrict__ c2w2,
                                                   const float* __restrict__ c3w2,
                                                   const float* __restrict__ c1w1,
                                                   const float* __restrict__ c1b1,
                                                   const float* __restrict__ c2w1,
                                                   const float* __restrict__ c3w1,
                                                   const float* __restrict__ mw2,
                                                   const float* __restrict__ mw3,
                                                   ushort_t* __restrict__ w1fh,
                                                   ushort_t* __restrict__ w1fl,
                                                   ushort_t* __restrict__ w2fh,
                                                   ushort_t* __restrict__ w2fl,
                                                   float* __restrict__ wuv,
                                                   ushort_t* __restrict__ wuvfh,
                                                   ushort_t* __restrict__ wuvfl,
                                                   ushort_t* __restrict__ w23fh,
                                                   ushort_t* __restrict__ w23fl,
                                                   const float* __restrict__ pts,
                                                   int* __restrict__ idx_out) {
    __shared__ u64_t keys[NPTS];                 // used only by sort blocks (8 KB)
    int blk = blockIdx.x;
    if (blk < 96) {
        int t = blk * 256 + threadIdx.x;         // 0..24575
        int e = t & 7;
        int lane = (t >> 3) & 63;
        int fs = t >> 9;                         // frag id = nt*6+ks, 0..47
        int nt = fs / 6, ks = fs - nt * 6;
        int m = lane & 15, quad = lane >> 4;
        int k = ks * 32 + quad * 8 + e;
        int n = nt * 16 + m;
        float w = mw1[k * 128 + n];
        uint_t bits = __float_as_uint(w);
        float hif = __uint_as_float(bits & 0xFFFF0000u);
        w1fh[t] = (ushort_t)(bits >> 16);
        w1fl[t] = f2bf(w - hif);
    } else if (blk < 144) {
        int layer = (blk - 96) >> 4;             // 0..2
        const float* w2 = layer == 0 ? c1w2 : (layer == 1 ? c2w2 : c3w2);
        int t = ((blk - 96) & 15) * 256 + threadIdx.x;   // 0..4095
        int e = t & 7;
        int lane = (t >> 3) & 63;
        int fs = t >> 9;                         // frag id = ct*2+kh, 0..7
        int ct = fs >> 1, kh = fs & 1;
        int m = lane & 15, quad = lane >> 4;
        int k = kh * 32 + quad * 8 + e;
        int n = ct * 16 + m;
        float w = w2[k * 64 + n];
        uint_t bits = __float_as_uint(w);
        float hif = __uint_as_float(bits & 0xFFFF0000u);
        w2fh[layer * 4096 + t] = (ushort_t)(bits >> 16);
        w2fl[layer * 4096 + t] = f2bf(w - hif);
    } else if (blk == 144) {
        // layer-1 uv constants: wuv[arr*1024 + lane*16 + kh*8 + e]
        for (int s = threadIdx.x; s < 3072; s += 256) {
            int arr = s >> 10, r = s & 1023;
            int lane = r >> 4, ce = r & 15;
            int kh = ce >> 3, e = ce & 7;
            int quad = lane >> 4;
            int c = kh * 32 + quad * 8 + e;
            float val = (arr == 0) ? (c1w1[c] - c1w1[64 + c])
                      : (arr == 1) ? c1w1[64 + c] : c1b1[c];
            wuv[s] = val;
        }
    } else if (blk < 209) {
        // uv B-frags: B[n][k], n<64: wd = w1a-w1b, n>=64: wb = w1b
        int layer = (blk - 145) >> 5;            // 0 -> c2w1, 1 -> c3w1
        const float* w1 = layer == 0 ? c2w1 : c3w1;
        int t = ((blk - 145) & 31) * 256 + threadIdx.x;  // 0..8191
        int e = t & 7;
        int lane = (t >> 3) & 63;
        int fs = t >> 9;                         // frag id = nt*2+ks, 0..15
        int nt = fs >> 1, ks = fs & 1;
        int m = lane & 15, quad = lane >> 4;
        int k = ks * 32 + quad * 8 + e;
        float w;
        if (nt < 4) {
            int n = nt * 16 + m;
            w = w1[k * 64 + n] - w1[(64 + k) * 64 + n];
        } else {
            int n = (nt - 4) * 16 + m;
            w = w1[(64 + k) * 64 + n];
        }
        uint_t bits = __float_as_uint(w);
        float hif = __uint_as_float(bits & 0xFFFF0000u);
        wuvfh[layer * 8192 + t] = (ushort_t)(bits >> 16);
        wuvfl[layer * 8192 + t] = f2bf(w - hif);
    } else if (blk < 241) {
        // mlp layer-2 frags: mw2 [128][64], fs = nt*4+ks (nt<4, ks<4)
        int t = (blk - 209) * 256 + threadIdx.x;         // 0..8191
        int e = t & 7;
        int lane = (t >> 3) & 63;
        int fs = t >> 9;
        int nt = fs >> 2, ks = fs & 3;
        int m = lane & 15, quad = lane >> 4;
        int k = ks * 32 + quad * 8 + e;
        int n = nt * 16 + m;
        float w = mw2[k * 64 + n];
        uint_t bits = __float_as_uint(w);
        float hif = __uint_as_float(bits & 0xFFFF0000u);
        w23fh[t] = (ushort_t)(bits >> 16);
        w23fl[t] = f2bf(w - hif);
    } else if (blk < 249) {
        // mlp layer-3 frags: mw3 [64][32], fs = nt*2+ks (nt<2, ks<2)
        int t = (blk - 241) * 256 + threadIdx.x;         // 0..2047
        int e = t & 7;
        int lane = (t >> 3) & 63;
        int fs = t >> 9;
        int nt = fs >> 1, ks = fs & 1;
        int m = lane & 15, quad = lane >> 4;
        int k = ks * 32 + quad * 8 + e;
        int n = nt * 16 + m;
        float w = mw3[k * 32 + n];
        uint_t bits = __float_as_uint(w);
        float hif = __uint_as_float(bits & 0xFFFF0000u);
        w23fh[8192 + t] = (ushort_t)(bits >> 16);
        w23fl[8192 + t] = f2bf(w - hif);
    } else {
        // ---- layer-1 knn (C=1): bitonic sort + window ----
        int b = blk - 249;                       // batch 0..63
        int t = threadIdx.x;
        const float* base = pts + (size_t)b * NPTS;
        for (int s = t; s < NPTS; s += 256)
            keys[s] = ((u64_t)f2ord(base[s]) << 32) | (uint_t)s;
        for (int k = 2; k <= NPTS; k <<= 1) {
            for (int j2 = k >> 1; j2 > 0; j2 >>= 1) {
                __syncthreads();
                for (int i = t; i < NPTS; i += 256) {
                    int ix = i ^ j2;
                    if (ix > i) {
                        bool asc = ((i & k) == 0);
                        u64_t a = keys[i], c = keys[ix];
                        if ((a > c) == asc) { keys[i] = c; keys[ix] = a; }
                    }
                }
            }
        }
        __syncthreads();
        for (int s = t; s < NPTS; s += 256) {
            u64_t me = keys[s];
            int jme = (int)(me & 0x3FFu);
            uint_t mo = (uint_t)(me >> 32);
            uint_t mu = (mo & 0x80000000u) ? (mo ^ 0x80000000u) : ~mo;
            float xs = __uint_as_float(mu);
            uint_t lst[KNB];
            #pragma unroll
            for (int k = 0; k < KNB; ++k) lst[k] = 0xFFFFFFFFu;
            int lo = s - 16; if (lo < 0) lo = 0;
            int hi = s + 16; if (hi > NPTS - 1) hi = NPTS - 1;
            for (int q = lo; q <= hi; ++q) {
                u64_t o = keys[q];
                uint_t oo = (uint_t)(o >> 32);
                uint_t ou = (oo & 0x80000000u) ? (oo ^ 0x80000000u) : ~oo;
                float xo = __uint_as_float(ou);
                float d = (xs - xo) * (xs - xo);
                insert16(lst, packdj(d, (int)(o & 0x3FFu)));
            }
            int* op = idx_out + ((size_t)b * NPTS + jme) * KNB;
            #pragma unroll
            for (int k = 0; k < KNB; ++k) op[k] = (int)(lst[k] & 0x3FFu);
        }
    }
}

// ---------------- FUSED MFMA knn + uv: sequential roles, uniform block duration ----
// knn part = r8/r11 floor config; uv tail per wave (r12, +8.8 us net win).
// r13 polish: the uv A-fragments (UAh/UAl) are hoisted to the TOP, adjacent to
// the knn A-frag loads (same cache lines; runtime-indexing Ah[wave] would
// scratch-spill per rule #20). Their latency now amortizes over the whole
// insert phase instead of being exposed at the tail after the barrier.
__global__ __launch_bounds__(256, 4) void knnuv_kernel(const ushort_t* __restrict__ xh,
                                                       const ushort_t* __restrict__ xl,
                                                       const float* __restrict__ sq,
                                                       int* __restrict__ idx_out,
                                                       const ushort_t* __restrict__ wufh,
                                                       const ushort_t* __restrict__ wufl,
                                                       const float* __restrict__ b1,
                                                       float* __restrict__ u,
                                                       float* __restrict__ v) {
    constexpr int JC = NPTS / 4;                 // 256 j per chunk(=wave)
    __shared__ uint_t dbuf[4][16 * 68];
    __shared__ float sqs[4][JC];
    __shared__ uint_t mlst[4][64][17];           // [chunk][i-lane][k], stride-17
    int b    = blockIdx.x & 63;
    int ib   = blockIdx.x >> 6;                  // 0..15
    int wave = threadIdx.x >> 6;                 // = chunk
    int lane = threadIdx.x & 63;
    int i0   = b * NPTS + ib * 64;
    int m = lane & 15, quad = lane >> 4;
    int j0c = wave * JC;

    for (int t = lane; t < JC; t += 64) sqs[wave][t] = sq[b * NPTS + j0c + t];

    bf16x8_t Ah[4][2], Al[4][2];
    #pragma unroll
    for (int it = 0; it < 4; ++it) {
        #pragma unroll
        for (int kh = 0; kh < 2; ++kh) {
            size_t off = ((size_t)(i0 + it * 16 + m)) * 64 + kh * 32 + quad * 8;
            Ah[it][kh] = *(const bf16x8_t*)(xh + off);
            Al[it][kh] = *(const bf16x8_t*)(xl + off);
        }
    }
    // uv A-frags, hoisted (L1-hot: same lines as Ah[wave]/Al[wave]); +16 VGPR.
    int p0u = i0 + wave * 16;
    bf16x8_t UAh[2], UAl[2];
    #pragma unroll
    for (int ks = 0; ks < 2; ++ks) {
        size_t aoff = (size_t)(p0u + m) * 64 + ks * 32 + quad * 8;
        UAh[ks] = *(const bf16x8_t*)(xh + aoff);
        UAl[ks] = *(const bf16x8_t*)(xl + aoff);
    }
    float4 sqi[4];
    #pragma unroll
    for (int it = 0; it < 4; ++it)
        sqi[it] = *(const float4*)&sq[i0 + it * 16 + quad * 4];

    uint_t lst[KNB];
    #pragma unroll
    for (int k = 0; k < KNB; ++k) lst[k] = 0xFFFFFFFFu;

    for (int g = 0; g < JC / 16; ++g) {
        int jg = j0c + g * 16;                       // batch-local j base
        size_t boff = ((size_t)(b * NPTS + jg + m)) * 64 + quad * 8;
        bf16x8_t Bh0 = *(const bf16x8_t*)(xh + boff);
        bf16x8_t Bh1 = *(const bf16x8_t*)(xh + boff + 32);
        bf16x8_t Bl0 = *(const bf16x8_t*)(xl + boff);
        bf16x8_t Bl1 = *(const bf16x8_t*)(xl + boff + 32);
        float sqj = sqs[wave][g * 16 + m];
        int jm = jg + m;
        #pragma unroll
        for (int it = 0; it < 4; ++it) {
            f32x4_t acc = {0.f, 0.f, 0.f, 0.f};
            acc = __builtin_amdgcn_mfma_f32_16x16x32_bf16(Ah[it][0], Bh0, acc, 0, 0, 0);
            acc = __builtin_amdgcn_mfma_f32_16x16x32_bf16(Ah[it][1], Bh1, acc, 0, 0, 0);
            acc = __builtin_amdgcn_mfma_f32_16x16x32_bf16(Ah[it][0], Bl0, acc, 0, 0, 0);
            acc = __builtin_amdgcn_mfma_f32_16x16x32_bf16(Ah[it][1], Bl1, acc, 0, 0, 0);
            acc = __builtin_amdgcn_mfma_f32_16x16x32_bf16(Al[it][0], Bh0, acc, 0, 0, 0);
            acc = __builtin_amdgcn_mfma_f32_16x16x32_bf16(Al[it][1], Bh1, acc, 0, 0, 0);
            uint4 pv;
            pv.x = packdj(sqi[it].x + sqj - 2.0f * acc[0], jm);
            pv.y = packdj(sqi[it].y + sqj - 2.0f * acc[1], jm);
            pv.z = packdj(sqi[it].z + sqj - 2.0f * acc[2], jm);
            pv.w = packdj(sqi[it].w + sqj - 2.0f * acc[3], jm);
            *(uint4*)&dbuf[wave][m * 68 + it * 16 + quad * 4] = pv;
        }
        // dbuf is wave-private: ds-ordering within the wave, no barrier.
        #pragma unroll
        for (int jj = 0; jj < 16; ++jj)
            insert16(lst, dbuf[wave][jj * 68 + lane]);
    }
    #pragma unroll
    for (int k = 0; k < KNB; ++k) mlst[wave][lane][k] = lst[k];
    __syncthreads();
    if (wave == 0) {
        // wave0's own lst is live in registers; merge the other 3 sorted lists.
        uint_t bl[KNB];
        #pragma unroll
        for (int c = 1; c < 4; ++c) {
            #pragma unroll
            for (int k = 0; k < KNB; ++k) bl[k] = mlst[c][lane][k];
            merge16(lst, bl);
        }
        int* op = idx_out + (size_t)(i0 + lane) * KNB;
        #pragma unroll
        for (int k = 0; k < KNB; ++k) op[k] = (int)(lst[k] & 0x3FFu);
    }
    // ---- uv tail: wave handles its own 16 points (M=16, N=128=[u|v], K=64) ----
    f32x4_t uacc[8];
    #pragma unroll
    for (int nt = 0; nt < 8; ++nt) uacc[nt] = (f32x4_t){0.f, 0.f, 0.f, 0.f};
    #pragma unroll
    for (int ks = 0; ks < 2; ++ks) {
        #pragma unroll
        for (int nt = 0; nt < 8; ++nt) {
            size_t boff = (size_t)((nt * 2 + ks) * 64 + lane) * 8;
            bf16x8_t Bh = *(const bf16x8_t*)(wufh + boff);
            bf16x8_t Bl = *(const bf16x8_t*)(wufl + boff);
            uacc[nt] = __builtin_amdgcn_mfma_f32_16x16x32_bf16(UAh[ks], Bh, uacc[nt], 0, 0, 0);
            uacc[nt] = __builtin_amdgcn_mfma_f32_16x16x32_bf16(UAh[ks], Bl, uacc[nt], 0, 0, 0);
            uacc[nt] = __builtin_amdgcn_mfma_f32_16x16x32_bf16(UAl[ks], Bh, uacc[nt], 0, 0, 0);
        }
    }
    // C: row = quad*4+reg = point-in-wave, col = m = n-in-tile
    #pragma unroll
    for (int nt = 0; nt < 8; ++nt) {
        int ch = (nt & 3) * 16 + m;
        float bb = (nt < 4) ? b1[ch] : 0.f;
        float* dst = (nt < 4) ? u : v;
        #pragma unroll
        for (int rr = 0; rr < 4; ++rr) {
            int p = p0u + quad * 4 + rr;
            dst[(size_t)p * 64 + ch] = uacc[nt][rr] + bb;
        }
    }
}

// ---------------- edge1 MFMA (layer 1, C_in=1): u/v never materialized ----------------
__global__ __launch_bounds__(256) void edge1_mfma_kernel(const float* __restrict__ x0,
                                                         const int* __restrict__ idx,
                                                         const ushort_t* __restrict__ w2fh,
                                                         const ushort_t* __restrict__ w2fl,
                                                         const float* __restrict__ wuv,
                                                         const float* __restrict__ b2,
                                                         ushort_t* __restrict__ oh,
                                                         ushort_t* __restrict__ ol,
                                                         float* __restrict__ sqout) {
    int wave = threadIdx.x >> 6, lane = threadIdx.x & 63;
    int m = lane & 15, quad = lane >> 4;
    bf16x8_t Bh[4][2], Bl[4][2];
    #pragma unroll
    for (int ct = 0; ct < 4; ++ct) {
        #pragma unroll
        for (int kh = 0; kh < 2; ++kh) {
            size_t boff = (size_t)((ct * 2 + kh) * 64 + lane) * 8;
            Bh[ct][kh] = *(const bf16x8_t*)(w2fh + boff);
            Bl[ct][kh] = *(const bf16x8_t*)(w2fl + boff);
        }
    }
    float wdv[16], wbv[16], bbv[16];
    #pragma unroll
    for (int q = 0; q < 4; ++q) {
        *(float4*)&wdv[q * 4] = *(const float4*)&wuv[lane * 16 + q * 4];
        *(float4*)&wbv[q * 4] = *(const float4*)&wuv[1024 + lane * 16 + q * 4];
        *(float4*)&bbv[q * 4] = *(const float4*)&wuv[2048 + lane * 16 + q * 4];
    }
    float bias[4];
    #pragma unroll
    for (int ct = 0; ct < 4; ++ct) bias[ct] = b2[ct * 16 + m];
    int bb_ = blockIdx.x & 63;                  // batch (XCD-pinned)
    int r_  = blockIdx.x >> 6;                  // 0..63 within batch
    int p0 = bb_ * NPTS + r_ * 16 + wave * 4;
    int jv[4];
    #pragma unroll
    for (int pi = 0; pi < 4; ++pi) jv[pi] = idx[(p0 + pi) * 16 + m];
    float xj4[4];
    #pragma unroll
    for (int pi = 0; pi < 4; ++pi) xj4[pi] = x0[(bb_ << 10) + jv[pi]];
    #pragma unroll
    for (int pi = 0; pi < 4; ++pi) {
        int p = p0 + pi;
        float xi = x0[p];                       // wave-uniform
        float xj = xj4[pi];                     // per A-row (neighbor m)
        bf16x8_t Ah[2], Al[2];
        #pragma unroll
        for (int kh = 0; kh < 2; ++kh) {
            float g[8];
            #pragma unroll
            for (int e = 0; e < 8; ++e) {
                int ce = kh * 8 + e;
                g[e] = fmaxf(fmaf(xi, wdv[ce], fmaf(xj, wbv[ce], bbv[ce])), 0.f);
            }
            pack_hilo8(g, &Ah[kh], &Al[kh]);
        }
        float val[4];
        #pragma unroll
        for (int ct = 0; ct < 4; ++ct) {
            f32x4_t acc = {0.f, 0.f, 0.f, 0.f};
            acc = __builtin_amdgcn_mfma_f32_16x16x32_bf16(Ah[0], Bh[ct][0], acc, 0, 0, 0);
            acc = __builtin_amdgcn_mfma_f32_16x16x32_bf16(Ah[1], Bh[ct][1], acc, 0, 0, 0);
            acc = __builtin_amdgcn_mfma_f32_16x16x32_bf16(Ah[0], Bl[ct][0], acc, 0, 0, 0);
            acc = __builtin_amdgcn_mfma_f32_16x16x32_bf16(Ah[1], Bl[ct][1], acc, 0, 0, 0);
            acc = __builtin_amdgcn_mfma_f32_16x16x32_bf16(Al[0], Bh[ct][0], acc, 0, 0, 0);
            acc = __builtin_amdgcn_mfma_f32_16x16x32_bf16(Al[1], Bh[ct][1], acc, 0, 0, 0);
            float mm = fmaxf(fmaxf(acc[0], acc[1]), fmaxf(acc[2], acc[3]));
            mm = fmaxf(mm, __shfl_xor(mm, 16, 64));
            mm = fmaxf(mm, __shfl_xor(mm, 32, 64));
            val[ct] = mm + bias[ct];
        }
        {   // fused sqnorm
            float partial = val[0] * val[0] + val[1] * val[1]
                          + val[2] * val[2] + val[3] * val[3];
            partial += __shfl_xor(partial, 1, 64);
            partial += __shfl_xor(partial, 2, 64);
            partial += __shfl_xor(partial, 4, 64);
            partial += __shfl_xor(partial, 8, 64);
            if (lane == 0) sqout[p] = partial;
        }
        if (quad == 0) {
            #pragma unroll
            for (int ct = 0; ct < 4; ++ct) {
                int o = ct * 16 + m;
                float vv = val[ct];
                uint_t bits = __float_as_uint(vv);
                oh[(size_t)p * 64 + o] = (ushort_t)(bits >> 16);
                float hif = __uint_as_float(bits & 0xFFFF0000u);
                ol[(size_t)p * 64 + o] = f2bf(vv - hif);
            }
        }
    }
}

// ---------------- edge MFMA (layers 2/3): wave = 1 point/step, prefab w2 frags ----
template<bool WSQ>
__global__ __launch_bounds__(256) void edge_mfma_kernel(const float* __restrict__ u,
                                                        const float* __restrict__ v,
                                                        const int* __restrict__ idx,
                                                        const ushort_t* __restrict__ w2fh,
                                                        const ushort_t* __restrict__ w2fl,
                                                        const float* __restrict__ b2,
                                                        ushort_t* __restrict__ oh,
                                                        ushort_t* __restrict__ ol,
                                                        float* __restrict__ sqout) {
    int wave = threadIdx.x >> 6, lane = threadIdx.x & 63;
    int m = lane & 15, quad = lane >> 4;
    bf16x8_t Bh[4][2], Bl[4][2];
    #pragma unroll
    for (int ct = 0; ct < 4; ++ct) {
        #pragma unroll
        for (int kh = 0; kh < 2; ++kh) {
            size_t boff = (size_t)((ct * 2 + kh) * 64 + lane) * 8;
            Bh[ct][kh] = *(const bf16x8_t*)(w2fh + boff);
            Bl[ct][kh] = *(const bf16x8_t*)(w2fl + boff);
        }
    }
    float bias[4];
    #pragma unroll
    for (int ct = 0; ct < 4; ++ct) bias[ct] = b2[ct * 16 + m];
    int bb_ = blockIdx.x & 63;                  // batch (XCD-pinned)
    int r_  = blockIdx.x >> 6;                  // 0..63 within batch
    int p0 = bb_ * NPTS + r_ * 16 + wave * 4;
    int jv[4];
    #pragma unroll
    for (int pi = 0; pi < 4; ++pi) jv[pi] = idx[(p0 + pi) * 16 + m];
    #pragma unroll
    for (int pi = 0; pi < 4; ++pi) {
        int p = p0 + pi;
        const float* up = u + (size_t)p * 64;
        const float* vp = v + ((size_t)(bb_ << 10) + jv[pi]) * 64;
        bf16x8_t Ah[2], Al[2];
        #pragma unroll
        for (int kh = 0; kh < 2; ++kh) {
            int c0 = kh * 32 + quad * 8;
            float4 ua = *(const float4*)(up + c0);
            float4 ub = *(const float4*)(up + c0 + 4);
            float4 va = *(const float4*)(vp + c0);
            float4 vb = *(const float4*)(vp + c0 + 4);
            float g[8] = {fmaxf(ua.x + va.x, 0.f), fmaxf(ua.y + va.y, 0.f),
                          fmaxf(ua.z + va.z, 0.f), fmaxf(ua.w + va.w, 0.f),
                          fmaxf(ub.x + vb.x, 0.f), fmaxf(ub.y + vb.y, 0.f),
                          fmaxf(ub.z + vb.z, 0.f), fmaxf(ub.w + vb.w, 0.f)};
            pack_hilo8(g, &Ah[kh], &Al[kh]);
        }
        float val[4];
        #pragma unroll
        for (int ct = 0; ct < 4; ++ct) {
            f32x4_t acc = {0.f, 0.f, 0.f, 0.f};
            acc = __builtin_amdgcn_mfma_f32_16x16x32_bf16(Ah[0], Bh[ct][0], acc, 0, 0, 0);
            acc = __builtin_amdgcn_mfma_f32_16x16x32_bf16(Ah[1], Bh[ct][1], acc, 0, 0, 0);
            acc = __builtin_amdgcn_mfma_f32_16x16x32_bf16(Ah[0], Bl[ct][0], acc, 0, 0, 0);
            acc = __builtin_amdgcn_mfma_f32_16x16x32_bf16(Ah[1], Bl[ct][1], acc, 0, 0, 0);
            acc = __builtin_amdgcn_mfma_f32_16x16x32_bf16(Al[0], Bh[ct][0], acc, 0, 0, 0);
            acc = __builtin_amdgcn_mfma_f32_16x16x32_bf16(Al[1], Bh[ct][1], acc, 0, 0, 0);
            float mm = fmaxf(fmaxf(acc[0], acc[1]), fmaxf(acc[2], acc[3]));
            mm = fmaxf(mm, __shfl_xor(mm, 16, 64));
            mm = fmaxf(mm, __shfl_xor(mm, 32, 64));   // mm now quad-uniform
            val[ct] = mm + bias[ct];
        }
        if constexpr (WSQ) {
            float partial = val[0] * val[0] + val[1] * val[1]
                          + val[2] * val[2] + val[3] * val[3];
            partial += __shfl_xor(partial, 1, 64);
            partial += __shfl_xor(partial, 2, 64);
            partial += __shfl_xor(partial, 4, 64);
            partial += __shfl_xor(partial, 8, 64);
            if (lane == 0) sqout[p] = partial;
        }
        if (quad == 0) {
            #pragma unroll
            for (int ct = 0; ct < 4; ++ct) {
                int o = ct * 16 + m;
                float vv = val[ct];
                uint_t bits = __float_as_uint(vv);
                oh[(size_t)p * 64 + o] = (ushort_t)(bits >> 16);
                float hif = __uint_as_float(bits & 0xFFFF0000u);
                ol[(size_t)p * 64 + o] = f2bf(vv - hif);
            }
        }
    }
}

// ---------------- final MLP: wave-private, barrier-free; layers 1-3 all MFMA ------
__global__ __launch_bounds__(128, 2) void mlp_kernel(const ushort_t* __restrict__ xh1,
                                                  const ushort_t* __restrict__ xl1,
                                                  const ushort_t* __restrict__ xh2,
                                                  const ushort_t* __restrict__ xl2,
                                                  const ushort_t* __restrict__ xh3,
                                                  const ushort_t* __restrict__ xl3,
                                                  const ushort_t* __restrict__ w1fh,
                                                  const ushort_t* __restrict__ w1fl,
                                                  const ushort_t* __restrict__ w23fh,
                                                  const ushort_t* __restrict__ w23fl,
                                                  const float* __restrict__ mb1,
                                                  const float* __restrict__ mb2,
                                                  const float* __restrict__ mb3,
                                                  const float* __restrict__ mw4, const float* __restrict__ mb4,
                                                  float* __restrict__ out) {
    __shared__ float smem[2][128 * 17];      // 8704 B per wave
    int wave = threadIdx.x >> 6, lane = threadIdx.x & 63;
    float* h1w = smem[wave];                 // [128][17]  [channel][point]
    float* h2w = smem[wave];                 // [64][17]   overlays h1 (written after all h1 reads)
    float* h3w = smem[wave] + 64 * 17;       // [32][17]   overlays h1's upper half
    int m = lane & 15, quad = lane >> 4;
    int pw = blockIdx.x * 32 + wave * 16;    // this wave's 16 points

    const ushort_t* HS[3] = {xh1, xh2, xh3};
    const ushort_t* LS[3] = {xl1, xl2, xl3};
    bf16x8_t Ah[6], Al[6];
    #pragma unroll
    for (int ks = 0; ks < 6; ++ks) {
        size_t aoff = (size_t)(pw + m) * 64 + (ks & 1) * 32 + quad * 8;
        Ah[ks] = *(const bf16x8_t*)(HS[ks >> 1] + aoff);
        Al[ks] = *(const bf16x8_t*)(LS[ks >> 1] + aoff);
    }
    // ---- layer 1: [16 x 192] @ [192 x 128], MFMA ----
    f32x4_t acc1[8];
    #pragma unroll
    for (int nt = 0; nt < 8; ++nt) acc1[nt] = (f32x4_t){0.f, 0.f, 0.f, 0.f};
    #pragma unroll
    for (int ks = 0; ks < 6; ++ks) {
        bf16x8_t Bh[8], Bl[8];
        #pragma unroll
        for (int nt = 0; nt < 8; ++nt) {
            size_t boff = (size_t)(nt * 6 + ks) * 512 + lane * 8;
            Bh[nt] = *(const bf16x8_t*)(w1fh + boff);
            Bl[nt] = *(const bf16x8_t*)(w1fl + boff);
        }
        #pragma unroll
        for (int nt = 0; nt < 8; ++nt) {
            acc1[nt] = __builtin_amdgcn_mfma_f32_16x16x32_bf16(Ah[ks], Bh[nt], acc1[nt], 0, 0, 0);
            acc1[nt] = __builtin_amdgcn_mfma_f32_16x16x32_bf16(Ah[ks], Bl[nt], acc1[nt], 0, 0, 0);
            acc1[nt] = __builtin_amdgcn_mfma_f32_16x16x32_bf16(Al[ks], Bh[nt], acc1[nt], 0, 0, 0);
        }
    }
    #pragma unroll
    for (int nt = 0; nt < 8; ++nt) {
        float bb = mb1[nt * 16 + m];
        float4 w;
        w.x = fmaxf(acc1[nt][0] + bb, 0.f);
        w.y = fmaxf(acc1[nt][1] + bb, 0.f);
        w.z = fmaxf(acc1[nt][2] + bb, 0.f);
        w.w = fmaxf(acc1[nt][3] + bb, 0.f);
        *(float4*)&h1w[(nt * 16 + m) * 17 + quad * 4] = w;
    }
    // ---- layer 2: [16 x 128] @ [128 x 64], MFMA; A-frags from LDS hi/lo split ----
    f32x4_t acc2[4];
    #pragma unroll
    for (int nt = 0; nt < 4; ++nt) acc2[nt] = (f32x4_t){0.f, 0.f, 0.f, 0.f};
    #pragma unroll
    for (int ks = 0; ks < 4; ++ks) {
        union { ushort_t s[8]; bf16x8_t v8; } H, L;
        #pragma unroll
        for (int e = 0; e < 8; ++e) {
            float g = h1w[(ks * 32 + quad * 8 + e) * 17 + m];
            uint_t bits = __float_as_uint(g);
            H.s[e] = (ushort_t)(bits >> 16);
            float hif = __uint_as_float(bits & 0xFFFF0000u);
            L.s[e] = f2bf(g - hif);
        }
        bf16x8_t A2h = H.v8, A2l = L.v8;
        #pragma unroll
        for (int nt = 0; nt < 4; ++nt) {
            size_t boff = (size_t)(nt * 4 + ks) * 512 + lane * 8;
            bf16x8_t Bh = *(const bf16x8_t*)(w23fh + boff);
            bf16x8_t Bl = *(const bf16x8_t*)(w23fl + boff);
            acc2[nt] = __builtin_amdgcn_mfma_f32_16x16x32_bf16(A2h, Bh, acc2[nt], 0, 0, 0);
            acc2[nt] = __builtin_amdgcn_mfma_f32_16x16x32_bf16(A2h, Bl, acc2[nt], 0, 0, 0);
            acc2[nt] = __builtin_amdgcn_mfma_f32_16x16x32_bf16(A2l, Bh, acc2[nt], 0, 0, 0);
        }
    }
    #pragma unroll
    for (int nt = 0; nt < 4; ++nt) {
        float bb = mb2[nt * 16 + m];
        float4 w;
        w.x = fmaxf(acc2[nt][0] + bb, 0.f);
        w.y = fmaxf(acc2[nt][1] + bb, 0.f);
        w.z = fmaxf(acc2[nt][2] + bb, 0.f);
        w.w = fmaxf(acc2[nt][3] + bb, 0.f);
        *(float4*)&h2w[(nt * 16 + m) * 17 + quad * 4] = w;
    }
    // ---- layer 3: [16 x 64] @ [64 x 32], MFMA ----
    f32x4_t acc3[2];
    #pragma unroll
    for (int nt = 0; nt < 2; ++nt) acc3[nt] = (f32x4_t){0.f, 0.f, 0.f, 0.f};
    #pragma unroll
    for (int ks = 0; ks < 2; ++ks) {
        union { ushort_t s[8]; bf16x8_t v8; } H, L;
        #pragma unroll
        for (int e = 0; e < 8; ++e) {
            float g = h2w[(ks * 32 + quad * 8 + e) * 17 + m];
            uint_t bits = __float_as_uint(g);
            H.s[e] = (ushort_t)(bits >> 16);
            float hif = __uint_as_float(bits & 0xFFFF0000u);
            L.s[e] = f2bf(g - hif);
        }
        bf16x8_t A3h = H.v8, A3l = L.v8;
        #pragma unroll
        for (int nt = 0; nt < 2; ++nt) {
            size_t boff = (size_t)(8192 + (nt * 2 + ks) * 512) + lane * 8;
            bf16x8_t Bh = *(const bf16x8_t*)(w23fh + boff);
            bf16x8_t Bl = *(const bf16x8_t*)(w23fl + boff);
            acc3[nt] = __builtin_amdgcn_mfma_f32_16x16x32_bf16(A3h, Bh, acc3[nt], 0, 0, 0);
            acc3[nt] = __builtin_amdgcn_mfma_f32_16x16x32_bf16(A3h, Bl, acc3[nt], 0, 0, 0);
            acc3[nt] = __builtin_amdgcn_mfma_f32_16x16x32_bf16(A3l, Bh, acc3[nt], 0, 0, 0);
        }
    }
    #pragma unroll
    for (int nt = 0; nt < 2; ++nt) {
        float bb = mb3[nt * 16 + m];
        float4 w;
        w.x = fmaxf(acc3[nt][0] + bb, 0.f);
        w.y = fmaxf(acc3[nt][1] + bb, 0.f);
        w.z = fmaxf(acc3[nt][2] + bb, 0.f);
        w.w = fmaxf(acc3[nt][3] + bb, 0.f);
        *(float4*)&h3w[(nt * 16 + m) * 17 + quad * 4] = w;
    }
    // ---- layer 4 + log_softmax (tiny): lane<16 = point ----
    if (lane < 16) {
        float z0 = mb4[0], z1 = mb4[1];
        #pragma unroll 8
        for (int c = 0; c < 32; ++c) {
            float h = h3w[c * 17 + lane];
            z0 = fmaf(h, mw4[c * 2 + 0], z0);
            z1 = fmaf(h, mw4[c * 2 + 1], z1);
        }
        float mx = fmaxf(z0, z1);
        float ls = mx + logf(expf(z0 - mx) + expf(z1 - mx));
        float2 o; o.x = z0 - ls; o.y = z1 - ls;
        *(float2*)&out[(size_t)(pw + lane) * 2] = o;
    }
}

extern "C" void kernel_launch(void* const* d_in, const int* in_sizes, int n_in,
                              void* d_out, int out_size, void* d_ws, size_t ws_size,
                              hipStream_t stream) {
    const float* x0   = (const float*)d_in[0];
    const float* c1w1 = (const float*)d_in[1];  const float* c1b1 = (const float*)d_in[2];
    const float* c1w2 = (const float*)d_in[3];  const float* c1b2 = (const float*)d_in[4];
    const float* c2w1 = (const float*)d_in[5];  const float* c2b1 = (const float*)d_in[6];
    const float* c2w2 = (const float*)d_in[7];  const float* c2b2 = (const float*)d_in[8];
    const float* c3w1 = (const float*)d_in[9];  const float* c3b1 = (const float*)d_in[10];
    const float* c3w2 = (const float*)d_in[11]; const float* c3b2 = (const float*)d_in[12];
    const float* mw1  = (const float*)d_in[13]; const float* mb1  = (const float*)d_in[14];
    const float* mw2  = (const float*)d_in[15]; const float* mb2  = (const float*)d_in[16];
    const float* mw3  = (const float*)d_in[17]; const float* mb3  = (const float*)d_in[18];
    const float* mw4  = (const float*)d_in[19]; const float* mb4  = (const float*)d_in[20];

    float* ws = (float*)d_ws;
    const size_t NF = (size_t)NPOINTS * 64;
    float* u  = ws;
    float* v  = u + NF;
    float* sq = v + NF;
    int*  idx = (int*)(sq + NPOINTS);
    ushort_t* xh1 = (ushort_t*)(idx + (size_t)NPOINTS * KNB);
    ushort_t* xl1 = xh1 + NF;
    ushort_t* xh2 = xl1 + NF;
    ushort_t* xl2 = xh2 + NF;
    ushort_t* xh3 = xl2 + NF;
    ushort_t* xl3 = xh3 + NF;
    ushort_t* w1fh = xl3 + NF;
    ushort_t* w1fl = w1fh + 128 * 192;
    ushort_t* w2fh = w1fl + 128 * 192;       // 3 layers x 4096
    ushort_t* w2fl = w2fh + 3 * 4096;
    float* wuv = (float*)(w2fl + 3 * 4096);  // 3 x 1024 fp32 layer-1 uv consts
    ushort_t* wuvfh = (ushort_t*)(wuv + 3072);   // 2 layers x 8192
    ushort_t* wuvfl = wuvfh + 2 * 8192;
    ushort_t* w23fh = wuvfl + 2 * 8192;      // mlp w2 frags (8192) + w3 frags (2048)
    ushort_t* w23fl = w23fh + 10240;
    float* out = (float*)d_out;

    // ---- fused weight prep + layer-1 sort-knn (independent; overlapped) ----
    prep_kernel<<<313, 256, 0, stream>>>(mw1, c1w2, c2w2, c3w2, c1w1, c1b1,
                                         c2w1, c3w1, mw2, mw3,
                                         w1fh, w1fl, w2fh, w2fl,
                                         wuv, wuvfh, wuvfl, w23fh, w23fl,
                                         x0, idx);
    // ---- layer 1 (C_in = 1): uv-free edge ----
    edge1_mfma_kernel<<<NB * 64, 256, 0, stream>>>(
        x0, idx, w2fh, w2fl, wuv, c1b2, xh1, xl1, sq);
    // ---- layer 2: FUSED knn+uv (sequential in-block) + edge ----
    knnuv_kernel<<<NB * 16, 256, 0, stream>>>(xh1, xl1, sq, idx,
                                              wuvfh, wuvfl, c2b1, u, v);
    edge_mfma_kernel<true><<<NPOINTS / 16, 256, 0, stream>>>(
        u, v, idx, w2fh + 4096, w2fl + 4096, c2b2, xh2, xl2, sq);
    // ---- layer 3 ----
    knnuv_kernel<<<NB * 16, 256, 0, stream>>>(xh2, xl2, sq, idx,
                                              wuvfh + 8192, wuvfl + 8192, c3b1, u, v);
    edge_mfma_kernel<false><<<NPOINTS / 16, 256, 0, stream>>>(
        u, v, idx, w2fh + 8192, w2fl + 8192, c3b2, xh3, xl3, nullptr);
    // ---- final MLP + log_softmax ----
    mlp_kernel<<<NPOINTS / 32, 128, 0, stream>>>(xh1, xl1, xh2, xl2, xh3, xl3,
                                                 w1fh, w1fl, w23fh, w23fl,
                                                 mb1, mb2, mb3, mw4, mb4, out);
}

// Round 14
// 447.529 us; speedup vs baseline: 1.0109x; 1.0109x over previous
//
#include <hip/hip_runtime.h>
#include <math.h>

typedef unsigned short ushort_t;
typedef unsigned int uint_t;
typedef unsigned long long u64_t;
typedef __bf16 bf16x8_t __attribute__((ext_vector_type(8)));
typedef float f32x4_t __attribute__((ext_vector_type(4)));

static constexpr int NPTS = 1024;
static constexpr int NB = 64;
static constexpr int NPOINTS = NB * NPTS;   // 65536
static constexpr int KNB = 16;

__device__ __forceinline__ ushort_t f2bf(float f) {
    uint_t u = __float_as_uint(f);
    uint_t r = (u + 0x7FFFu + ((u >> 16) & 1u)) >> 16;
    return (ushort_t)r;
}
// pack distance (clamped >=0, 22 bits kept) + batch-local j (10 bits).
__device__ __forceinline__ uint_t packdj(float d, int j) {
    return (__float_as_uint(fmaxf(d, 0.f)) & 0xFFFFFC00u) | (uint_t)j;
}
// single-instruction median: for sorted L[k-1]<=L[k], post-insert
// L'[k] = med3(L[k-1], L[k], c). One VOP3 per step; all steps independent.
__device__ __forceinline__ uint_t med3u(uint_t a, uint_t b, uint_t c) {
    uint_t d;
    asm("v_med3_u32 %0, %1, %2, %3" : "=v"(d) : "v"(a), "v"(b), "v"(c));
    return d;
}
__device__ __forceinline__ void insert16(uint_t* L, uint_t c) {
    #pragma unroll
    for (int k = 15; k > 0; --k)
        L[k] = med3u(L[k - 1], L[k], c);
    L[0] = L[0] < c ? L[0] : c;
}
// Merge two ASCENDING sorted 16-lists, keep the 16 smallest, result ascending.
// t[k] = min(A[k], B[15-k]) is bitonic; 4-stage half-cleaner sorts it.
// 80 compare-exchange vs 272 VALU for 16x insert16. (Verified in-harness r7/r8.)
__device__ __forceinline__ void merge16(uint_t* L, const uint_t* B) {
    uint_t t[16];
    #pragma unroll
    for (int k = 0; k < 16; ++k) t[k] = L[k] < B[15 - k] ? L[k] : B[15 - k];
    #pragma unroll
    for (int j = 8; j >= 1; j >>= 1) {
        #pragma unroll
        for (int k = 0; k < 16; ++k) {
            if ((k & j) == 0) {
                uint_t a = t[k], c = t[k | j];
                t[k] = a < c ? a : c;
                t[k | j] = a < c ? c : a;
            }
        }
    }
    #pragma unroll
    for (int k = 0; k < 16; ++k) L[k] = t[k];
}
// monotone float->uint order transform
__device__ __forceinline__ uint_t f2ord(float f) {
    uint_t u = __float_as_uint(f);
    return (u & 0x80000000u) ? ~u : (u ^ 0x80000000u);
}

// Build hi/lo bf16x8 A-fragments from 8 relu'd floats with v_perm_b32 packing.
// H word q = (bits(g[2q])>>16) | (bits(g[2q+1]) & 0xFFFF0000)  -- one v_perm.
// L uses TRUNCATED low part (bit-identical to the previous shift/or sequence).
__device__ __forceinline__ void pack_hilo8(const float* g, bf16x8_t* Ah, bf16x8_t* Al) {
    union { uint_t w[4]; bf16x8_t v8; } H, L;
    #pragma unroll
    for (int q = 0; q < 4; ++q) {
        float g0 = g[2 * q], g1 = g[2 * q + 1];
        uint_t u0 = __float_as_uint(g0), u1 = __float_as_uint(g1);
        H.w[q] = __builtin_amdgcn_perm(u1, u0, 0x07060302u);
        float d0 = g0 - __uint_as_float(u0 & 0xFFFF0000u);
        float d1 = g1 - __uint_as_float(u1 & 0xFFFF0000u);
        L.w[q] = __builtin_amdgcn_perm(__float_as_uint(d1), __float_as_uint(d0),
                                       0x07060302u);
    }
    *Ah = H.v8; *Al = L.v8;
}

// ---------------- fused weight prep + layer-1 sort-knn ----------------
// blocks 0..95   : mlp w1 frags (24576)
// blocks 96..143 : 3x edge w2 frags (4096 each)
// block  144     : layer-1 uv scalar consts (3072 floats)
// blocks 145..208: 2x uv [wd|wb] frags for layers 2/3 (8192 each)
// blocks 209..240: mlp w2 frags (8192)
// blocks 241..248: mlp w3 frags (2048)
// blocks 249..312: layer-1 knn (C=1): bitonic sort + +/-16 window (1 batch each)
__global__ __launch_bounds__(256) void prep_kernel(const float* __restrict__ mw1,
                                                   const float* __restrict__ c1w2,
                                                   const float* __restrict__ c2w2,
                                                   const float* __restrict__ c3w2,
                                                   const float* __restrict__ c1w1,
                                                   const float* __restrict__ c1b1,
                                                   const float* __restrict__ c2w1,
                                                   const float* __restrict__ c3w1,
                                                   const float* __restrict__ mw2,
                                                   const float* __restrict__ mw3,
                                                   ushort_t* __restrict__ w1fh,
                                                   ushort_t* __restrict__ w1fl,
                                                   ushort_t* __restrict__ w2fh,
                                                   ushort_t* __restrict__ w2fl,
                                                   float* __restrict__ wuv,
                                                   ushort_t* __restrict__ wuvfh,
                                                   ushort_t* __restrict__ wuvfl,
                                                   ushort_t* __restrict__ w23fh,
                                                   ushort_t* __restrict__ w23fl,
                                                   const float* __restrict__ pts,
                                                   int* __restrict__ idx_out) {
    __shared__ u64_t keys[NPTS];                 // used only by sort blocks (8 KB)
    int blk = blockIdx.x;
    if (blk < 96) {
        int t = blk * 256 + threadIdx.x;         // 0..24575
        int e = t & 7;
        int lane = (t >> 3) & 63;
        int fs = t >> 9;                         // frag id = nt*6+ks, 0..47
        int nt = fs / 6, ks = fs - nt * 6;
        int m = lane & 15, quad = lane >> 4;
        int k = ks * 32 + quad * 8 + e;
        int n = nt * 16 + m;
        float w = mw1[k * 128 + n];
        uint_t bits = __float_as_uint(w);
        float hif = __uint_as_float(bits & 0xFFFF0000u);
        w1fh[t] = (ushort_t)(bits >> 16);
        w1fl[t] = f2bf(w - hif);
    } else if (blk < 144) {
        int layer = (blk - 96) >> 4;             // 0..2
        const float* w2 = layer == 0 ? c1w2 : (layer == 1 ? c2w2 : c3w2);
        int t = ((blk - 96) & 15) * 256 + threadIdx.x;   // 0..4095
        int e = t & 7;
        int lane = (t >> 3) & 63;
        int fs = t >> 9;                         // frag id = ct*2+kh, 0..7
        int ct = fs >> 1, kh = fs & 1;
        int m = lane & 15, quad = lane >> 4;
        int k = kh * 32 + quad * 8 + e;
        int n = ct * 16 + m;
        float w = w2[k * 64 + n];
        uint_t bits = __float_as_uint(w);
        float hif = __uint_as_float(bits & 0xFFFF0000u);
        w2fh[layer * 4096 + t] = (ushort_t)(bits >> 16);
        w2fl[layer * 4096 + t] = f2bf(w - hif);
    } else if (blk == 144) {
        // layer-1 uv constants: wuv[arr*1024 + lane*16 + kh*8 + e]
        for (int s = threadIdx.x; s < 3072; s += 256) {
            int arr = s >> 10, r = s & 1023;
            int lane = r >> 4, ce = r & 15;
            int kh = ce >> 3, e = ce & 7;
            int quad = lane >> 4;
            int c = kh * 32 + quad * 8 + e;
            float val = (arr == 0) ? (c1w1[c] - c1w1[64 + c])
                      : (arr == 1) ? c1w1[64 + c] : c1b1[c];
            wuv[s] = val;
        }
    } else if (blk < 209) {
        // uv B-frags: B[n][k], n<64: wd = w1a-w1b, n>=64: wb = w1b
        int layer = (blk - 145) >> 5;            // 0 -> c2w1, 1 -> c3w1
        const float* w1 = layer == 0 ? c2w1 : c3w1;
        int t = ((blk - 145) & 31) * 256 + threadIdx.x;  // 0..8191
        int e = t & 7;
        int lane = (t >> 3) & 63;
        int fs = t >> 9;                         // frag id = nt*2+ks, 0..15
        int nt = fs >> 1, ks = fs & 1;
        int m = lane & 15, quad = lane >> 4;
        int k = ks * 32 + quad * 8 + e;
        float w;
        if (nt < 4) {
            int n = nt * 16 + m;
            w = w1[k * 64 + n] - w1[(64 + k) * 64 + n];
        } else {
            int n = (nt - 4) * 16 + m;
            w = w1[(64 + k) * 64 + n];
        }
        uint_t bits = __float_as_uint(w);
        float hif = __uint_as_float(bits & 0xFFFF0000u);
        wuvfh[layer * 8192 + t] = (ushort_t)(bits >> 16);
        wuvfl[layer * 8192 + t] = f2bf(w - hif);
    } else if (blk < 241) {
        // mlp layer-2 frags: mw2 [128][64], fs = nt*4+ks (nt<4, ks<4)
        int t = (blk - 209) * 256 + threadIdx.x;         // 0..8191
        int e = t & 7;
        int lane = (t >> 3) & 63;
        int fs = t >> 9;
        int nt = fs >> 2, ks = fs & 3;
        int m = lane & 15, quad = lane >> 4;
        int k = ks * 32 + quad * 8 + e;
        int n = nt * 16 + m;
        float w = mw2[k * 64 + n];
        uint_t bits = __float_as_uint(w);
        float hif = __uint_as_float(bits & 0xFFFF0000u);
        w23fh[t] = (ushort_t)(bits >> 16);
        w23fl[t] = f2bf(w - hif);
    } else if (blk < 249) {
        // mlp layer-3 frags: mw3 [64][32], fs = nt*2+ks (nt<2, ks<2)
        int t = (blk - 241) * 256 + threadIdx.x;         // 0..2047
        int e = t & 7;
        int lane = (t >> 3) & 63;
        int fs = t >> 9;
        int nt = fs >> 1, ks = fs & 1;
        int m = lane & 15, quad = lane >> 4;
        int k = ks * 32 + quad * 8 + e;
        int n = nt * 16 + m;
        float w = mw3[k * 32 + n];
        uint_t bits = __float_as_uint(w);
        float hif = __uint_as_float(bits & 0xFFFF0000u);
        w23fh[8192 + t] = (ushort_t)(bits >> 16);
        w23fl[8192 + t] = f2bf(w - hif);
    } else {
        // ---- layer-1 knn (C=1): bitonic sort + window ----
        int b = blk - 249;                       // batch 0..63
        int t = threadIdx.x;
        const float* base = pts + (size_t)b * NPTS;
        for (int s = t; s < NPTS; s += 256)
            keys[s] = ((u64_t)f2ord(base[s]) << 32) | (uint_t)s;
        for (int k = 2; k <= NPTS; k <<= 1) {
            for (int j2 = k >> 1; j2 > 0; j2 >>= 1) {
                __syncthreads();
                for (int i = t; i < NPTS; i += 256) {
                    int ix = i ^ j2;
                    if (ix > i) {
                        bool asc = ((i & k) == 0);
                        u64_t a = keys[i], c = keys[ix];
                        if ((a > c) == asc) { keys[i] = c; keys[ix] = a; }
                    }
                }
            }
        }
        __syncthreads();
        for (int s = t; s < NPTS; s += 256) {
            u64_t me = keys[s];
            int jme = (int)(me & 0x3FFu);
            uint_t mo = (uint_t)(me >> 32);
            uint_t mu = (mo & 0x80000000u) ? (mo ^ 0x80000000u) : ~mo;
            float xs = __uint_as_float(mu);
            uint_t lst[KNB];
            #pragma unroll
            for (int k = 0; k < KNB; ++k) lst[k] = 0xFFFFFFFFu;
            int lo = s - 16; if (lo < 0) lo = 0;
            int hi = s + 16; if (hi > NPTS - 1) hi = NPTS - 1;
            for (int q = lo; q <= hi; ++q) {
                u64_t o = keys[q];
                uint_t oo = (uint_t)(o >> 32);
                uint_t ou = (oo & 0x80000000u) ? (oo ^ 0x80000000u) : ~oo;
                float xo = __uint_as_float(ou);
                float d = (xs - xo) * (xs - xo);
                insert16(lst, packdj(d, (int)(o & 0x3FFu)));
            }
            int* op = idx_out + ((size_t)b * NPTS + jme) * KNB;
            #pragma unroll
            for (int k = 0; k < KNB; ++k) op[k] = (int)(lst[k] & 0x3FFu);
        }
    }
}

// ---------------- FUSED MFMA knn + uv: sequential roles, uniform block duration ----
// knn part = r8/r11 floor config (69 us; issue-bound, not TLP-bound). After the
// merge phase each wave computes uv for its own 16 points (pure MFMA, no LDS):
// fills knn's 85%-idle matrix pipe across co-resident blocks, removes 2 uv
// dispatches + launch gaps. Unlike r7's parity split, every block has identical
// duration (no scheduling-locality blowup). uv A-frags are reloaded at the TAIL
// (L1-hot) -- r13's top-hoist variant regressed 76.2 -> 77.5 us (prologue VMEM
// contention), so tail placement is the measured optimum.
__global__ __launch_bounds__(256, 4) void knnuv_kernel(const ushort_t* __restrict__ xh,
                                                       const ushort_t* __restrict__ xl,
                                                       const float* __restrict__ sq,
                                                       int* __restrict__ idx_out,
                                                       const ushort_t* __restrict__ wufh,
                                                       const ushort_t* __restrict__ wufl,
                                                       const float* __restrict__ b1,
                                                       float* __restrict__ u,
                                                       float* __restrict__ v) {
    constexpr int JC = NPTS / 4;                 // 256 j per chunk(=wave)
    __shared__ uint_t dbuf[4][16 * 68];
    __shared__ float sqs[4][JC];
    __shared__ uint_t mlst[4][64][17];           // [chunk][i-lane][k], stride-17
    int b    = blockIdx.x & 63;
    int ib   = blockIdx.x >> 6;                  // 0..15
    int wave = threadIdx.x >> 6;                 // = chunk
    int lane = threadIdx.x & 63;
    int i0   = b * NPTS + ib * 64;
    int m = lane & 15, quad = lane >> 4;
    int j0c = wave * JC;

    for (int t = lane; t < JC; t += 64) sqs[wave][t] = sq[b * NPTS + j0c + t];

    bf16x8_t Ah[4][2], Al[4][2];
    #pragma unroll
    for (int it = 0; it < 4; ++it) {
        #pragma unroll
        for (int kh = 0; kh < 2; ++kh) {
            size_t off = ((size_t)(i0 + it * 16 + m)) * 64 + kh * 32 + quad * 8;
            Ah[it][kh] = *(const bf16x8_t*)(xh + off);
            Al[it][kh] = *(const bf16x8_t*)(xl + off);
        }
    }
    float4 sqi[4];
    #pragma unroll
    for (int it = 0; it < 4; ++it)
        sqi[it] = *(const float4*)&sq[i0 + it * 16 + quad * 4];

    uint_t lst[KNB];
    #pragma unroll
    for (int k = 0; k < KNB; ++k) lst[k] = 0xFFFFFFFFu;

    for (int g = 0; g < JC / 16; ++g) {
        int jg = j0c + g * 16;                       // batch-local j base
        size_t boff = ((size_t)(b * NPTS + jg + m)) * 64 + quad * 8;
        bf16x8_t Bh0 = *(const bf16x8_t*)(xh + boff);
        bf16x8_t Bh1 = *(const bf16x8_t*)(xh + boff + 32);
        bf16x8_t Bl0 = *(const bf16x8_t*)(xl + boff);
        bf16x8_t Bl1 = *(const bf16x8_t*)(xl + boff + 32);
        float sqj = sqs[wave][g * 16 + m];
        int jm = jg + m;
        #pragma unroll
        for (int it = 0; it < 4; ++it) {
            f32x4_t acc = {0.f, 0.f, 0.f, 0.f};
            acc = __builtin_amdgcn_mfma_f32_16x16x32_bf16(Ah[it][0], Bh0, acc, 0, 0, 0);
            acc = __builtin_amdgcn_mfma_f32_16x16x32_bf16(Ah[it][1], Bh1, acc, 0, 0, 0);
            acc = __builtin_amdgcn_mfma_f32_16x16x32_bf16(Ah[it][0], Bl0, acc, 0, 0, 0);
            acc = __builtin_amdgcn_mfma_f32_16x16x32_bf16(Ah[it][1], Bl1, acc, 0, 0, 0);
            acc = __builtin_amdgcn_mfma_f32_16x16x32_bf16(Al[it][0], Bh0, acc, 0, 0, 0);
            acc = __builtin_amdgcn_mfma_f32_16x16x32_bf16(Al[it][1], Bh1, acc, 0, 0, 0);
            uint4 pv;
            pv.x = packdj(sqi[it].x + sqj - 2.0f * acc[0], jm);
            pv.y = packdj(sqi[it].y + sqj - 2.0f * acc[1], jm);
            pv.z = packdj(sqi[it].z + sqj - 2.0f * acc[2], jm);
            pv.w = packdj(sqi[it].w + sqj - 2.0f * acc[3], jm);
            *(uint4*)&dbuf[wave][m * 68 + it * 16 + quad * 4] = pv;
        }
        // dbuf is wave-private: ds-ordering within the wave, no barrier.
        #pragma unroll
        for (int jj = 0; jj < 16; ++jj)
            insert16(lst, dbuf[wave][jj * 68 + lane]);
    }
    #pragma unroll
    for (int k = 0; k < KNB; ++k) mlst[wave][lane][k] = lst[k];
    __syncthreads();
    if (wave == 0) {
        // wave0's own lst is live in registers; merge the other 3 sorted lists.
        uint_t bl[KNB];
        #pragma unroll
        for (int c = 1; c < 4; ++c) {
            #pragma unroll
            for (int k = 0; k < KNB; ++k) bl[k] = mlst[c][lane][k];
            merge16(lst, bl);
        }
        int* op = idx_out + (size_t)(i0 + lane) * KNB;
        #pragma unroll
        for (int k = 0; k < KNB; ++k) op[k] = (int)(lst[k] & 0x3FFu);
    }
    // ---- uv tail: wave handles its own 16 points (M=16, N=128=[u|v], K=64) ----
    int p0u = i0 + wave * 16;
    bf16x8_t UAh[2], UAl[2];
    #pragma unroll
    for (int ks = 0; ks < 2; ++ks) {
        size_t aoff = (size_t)(p0u + m) * 64 + ks * 32 + quad * 8;   // L1-hot
        UAh[ks] = *(const bf16x8_t*)(xh + aoff);
        UAl[ks] = *(const bf16x8_t*)(xl + aoff);
    }
    f32x4_t uacc[8];
    #pragma unroll
    for (int nt = 0; nt < 8; ++nt) uacc[nt] = (f32x4_t){0.f, 0.f, 0.f, 0.f};
    #pragma unroll
    for (int ks = 0; ks < 2; ++ks) {
        #pragma unroll
        for (int nt = 0; nt < 8; ++nt) {
            size_t boff = (size_t)((nt * 2 + ks) * 64 + lane) * 8;
            bf16x8_t Bh = *(const bf16x8_t*)(wufh + boff);
            bf16x8_t Bl = *(const bf16x8_t*)(wufl + boff);
            uacc[nt] = __builtin_amdgcn_mfma_f32_16x16x32_bf16(UAh[ks], Bh, uacc[nt], 0, 0, 0);
            uacc[nt] = __builtin_amdgcn_mfma_f32_16x16x32_bf16(UAh[ks], Bl, uacc[nt], 0, 0, 0);
            uacc[nt] = __builtin_amdgcn_mfma_f32_16x16x32_bf16(UAl[ks], Bh, uacc[nt], 0, 0, 0);
        }
    }
    // C: row = quad*4+reg = point-in-wave, col = m = n-in-tile
    #pragma unroll
    for (int nt = 0; nt < 8; ++nt) {
        int ch = (nt & 3) * 16 + m;
        float bb = (nt < 4) ? b1[ch] : 0.f;
        float* dst = (nt < 4) ? u : v;
        #pragma unroll
        for (int rr = 0; rr < 4; ++rr) {
            int p = p0u + quad * 4 + rr;
            dst[(size_t)p * 64 + ch] = uacc[nt][rr] + bb;
        }
    }
}

// ---------------- edge1 MFMA (layer 1, C_in=1): u/v never materialized ----------------
__global__ __launch_bounds__(256) void edge1_mfma_kernel(const float* __restrict__ x0,
                                                         const int* __restrict__ idx,
                                                         const ushort_t* __restrict__ w2fh,
                                                         const ushort_t* __restrict__ w2fl,
                                                         const float* __restrict__ wuv,
                                                         const float* __restrict__ b2,
                                                         ushort_t* __restrict__ oh,
                                                         ushort_t* __restrict__ ol,
                                                         float* __restrict__ sqout) {
    int wave = threadIdx.x >> 6, lane = threadIdx.x & 63;
    int m = lane & 15, quad = lane >> 4;
    bf16x8_t Bh[4][2], Bl[4][2];
    #pragma unroll
    for (int ct = 0; ct < 4; ++ct) {
        #pragma unroll
        for (int kh = 0; kh < 2; ++kh) {
            size_t boff = (size_t)((ct * 2 + kh) * 64 + lane) * 8;
            Bh[ct][kh] = *(const bf16x8_t*)(w2fh + boff);
            Bl[ct][kh] = *(const bf16x8_t*)(w2fl + boff);
        }
    }
    float wdv[16], wbv[16], bbv[16];
    #pragma unroll
    for (int q = 0; q < 4; ++q) {
        *(float4*)&wdv[q * 4] = *(const float4*)&wuv[lane * 16 + q * 4];
        *(float4*)&wbv[q * 4] = *(const float4*)&wuv[1024 + lane * 16 + q * 4];
        *(float4*)&bbv[q * 4] = *(const float4*)&wuv[2048 + lane * 16 + q * 4];
    }
    float bias[4];
    #pragma unroll
    for (int ct = 0; ct < 4; ++ct) bias[ct] = b2[ct * 16 + m];
    int bb_ = blockIdx.x & 63;                  // batch (XCD-pinned)
    int r_  = blockIdx.x >> 6;                  // 0..63 within batch
    int p0 = bb_ * NPTS + r_ * 16 + wave * 4;
    int jv[4];
    #pragma unroll
    for (int pi = 0; pi < 4; ++pi) jv[pi] = idx[(p0 + pi) * 16 + m];
    float xj4[4];
    #pragma unroll
    for (int pi = 0; pi < 4; ++pi) xj4[pi] = x0[(bb_ << 10) + jv[pi]];
    #pragma unroll
    for (int pi = 0; pi < 4; ++pi) {
        int p = p0 + pi;
        float xi = x0[p];                       // wave-uniform
        float xj = xj4[pi];                     // per A-row (neighbor m)
        bf16x8_t Ah[2], Al[2];
        #pragma unroll
        for (int kh = 0; kh < 2; ++kh) {
            float g[8];
            #pragma unroll
            for (int e = 0; e < 8; ++e) {
                int ce = kh * 8 + e;
                g[e] = fmaxf(fmaf(xi, wdv[ce], fmaf(xj, wbv[ce], bbv[ce])), 0.f);
            }
            pack_hilo8(g, &Ah[kh], &Al[kh]);
        }
        float val[4];
        #pragma unroll
        for (int ct = 0; ct < 4; ++ct) {
            f32x4_t acc = {0.f, 0.f, 0.f, 0.f};
            acc = __builtin_amdgcn_mfma_f32_16x16x32_bf16(Ah[0], Bh[ct][0], acc, 0, 0, 0);
            acc = __builtin_amdgcn_mfma_f32_16x16x32_bf16(Ah[1], Bh[ct][1], acc, 0, 0, 0);
            acc = __builtin_amdgcn_mfma_f32_16x16x32_bf16(Ah[0], Bl[ct][0], acc, 0, 0, 0);
            acc = __builtin_amdgcn_mfma_f32_16x16x32_bf16(Ah[1], Bl[ct][1], acc, 0, 0, 0);
            acc = __builtin_amdgcn_mfma_f32_16x16x32_bf16(Al[0], Bh[ct][0], acc, 0, 0, 0);
            acc = __builtin_amdgcn_mfma_f32_16x16x32_bf16(Al[1], Bh[ct][1], acc, 0, 0, 0);
            float mm = fmaxf(fmaxf(acc[0], acc[1]), fmaxf(acc[2], acc[3]));
            mm = fmaxf(mm, __shfl_xor(mm, 16, 64));
            mm = fmaxf(mm, __shfl_xor(mm, 32, 64));
            val[ct] = mm + bias[ct];
        }
        {   // fused sqnorm
            float partial = val[0] * val[0] + val[1] * val[1]
                          + val[2] * val[2] + val[3] * val[3];
            partial += __shfl_xor(partial, 1, 64);
            partial += __shfl_xor(partial, 2, 64);
            partial += __shfl_xor(partial, 4, 64);
            partial += __shfl_xor(partial, 8, 64);
            if (lane == 0) sqout[p] = partial;
        }
        if (quad == 0) {
            #pragma unroll
            for (int ct = 0; ct < 4; ++ct) {
                int o = ct * 16 + m;
                float vv = val[ct];
                uint_t bits = __float_as_uint(vv);
                oh[(size_t)p * 64 + o] = (ushort_t)(bits >> 16);
                float hif = __uint_as_float(bits & 0xFFFF0000u);
                ol[(size_t)p * 64 + o] = f2bf(vv - hif);
            }
        }
    }
}

// ---------------- edge MFMA (layers 2/3): wave = 1 point/step, prefab w2 frags ----
template<bool WSQ>
__global__ __launch_bounds__(256) void edge_mfma_kernel(const float* __restrict__ u,
                                                        const float* __restrict__ v,
                                                        const int* __restrict__ idx,
                                                        const ushort_t* __restrict__ w2fh,
                                                        const ushort_t* __restrict__ w2fl,
                                                        const float* __restrict__ b2,
                                                        ushort_t* __restrict__ oh,
                                                        ushort_t* __restrict__ ol,
                                                        float* __restrict__ sqout) {
    int wave = threadIdx.x >> 6, lane = threadIdx.x & 63;
    int m = lane & 15, quad = lane >> 4;
    bf16x8_t Bh[4][2], Bl[4][2];
    #pragma unroll
    for (int ct = 0; ct < 4; ++ct) {
        #pragma unroll
        for (int kh = 0; kh < 2; ++kh) {
            size_t boff = (size_t)((ct * 2 + kh) * 64 + lane) * 8;
            Bh[ct][kh] = *(const bf16x8_t*)(w2fh + boff);
            Bl[ct][kh] = *(const bf16x8_t*)(w2fl + boff);
        }
    }
    float bias[4];
    #pragma unroll
    for (int ct = 0; ct < 4; ++ct) bias[ct] = b2[ct * 16 + m];
    int bb_ = blockIdx.x & 63;                  // batch (XCD-pinned)
    int r_  = blockIdx.x >> 6;                  // 0..63 within batch
    int p0 = bb_ * NPTS + r_ * 16 + wave * 4;
    int jv[4];
    #pragma unroll
    for (int pi = 0; pi < 4; ++pi) jv[pi] = idx[(p0 + pi) * 16 + m];
    #pragma unroll
    for (int pi = 0; pi < 4; ++pi) {
        int p = p0 + pi;
        const float* up = u + (size_t)p * 64;
        const float* vp = v + ((size_t)(bb_ << 10) + jv[pi]) * 64;
        bf16x8_t Ah[2], Al[2];
        #pragma unroll
        for (int kh = 0; kh < 2; ++kh) {
            int c0 = kh * 32 + quad * 8;
            float4 ua = *(const float4*)(up + c0);
            float4 ub = *(const float4*)(up + c0 + 4);
            float4 va = *(const float4*)(vp + c0);
            float4 vb = *(const float4*)(vp + c0 + 4);
            float g[8] = {fmaxf(ua.x + va.x, 0.f), fmaxf(ua.y + va.y, 0.f),
                          fmaxf(ua.z + va.z, 0.f), fmaxf(ua.w + va.w, 0.f),
                          fmaxf(ub.x + vb.x, 0.f), fmaxf(ub.y + vb.y, 0.f),
                          fmaxf(ub.z + vb.z, 0.f), fmaxf(ub.w + vb.w, 0.f)};
            pack_hilo8(g, &Ah[kh], &Al[kh]);
        }
        float val[4];
        #pragma unroll
        for (int ct = 0; ct < 4; ++ct) {
            f32x4_t acc = {0.f, 0.f, 0.f, 0.f};
            acc = __builtin_amdgcn_mfma_f32_16x16x32_bf16(Ah[0], Bh[ct][0], acc, 0, 0, 0);
            acc = __builtin_amdgcn_mfma_f32_16x16x32_bf16(Ah[1], Bh[ct][1], acc, 0, 0, 0);
            acc = __builtin_amdgcn_mfma_f32_16x16x32_bf16(Ah[0], Bl[ct][0], acc, 0, 0, 0);
            acc = __builtin_amdgcn_mfma_f32_16x16x32_bf16(Ah[1], Bl[ct][1], acc, 0, 0, 0);
            acc = __builtin_amdgcn_mfma_f32_16x16x32_bf16(Al[0], Bh[ct][0], acc, 0, 0, 0);
            acc = __builtin_amdgcn_mfma_f32_16x16x32_bf16(Al[1], Bh[ct][1], acc, 0, 0, 0);
            float mm = fmaxf(fmaxf(acc[0], acc[1]), fmaxf(acc[2], acc[3]));
            mm = fmaxf(mm, __shfl_xor(mm, 16, 64));
            mm = fmaxf(mm, __shfl_xor(mm, 32, 64));   // mm now quad-uniform
            val[ct] = mm + bias[ct];
        }
        if constexpr (WSQ) {
            float partial = val[0] * val[0] + val[1] * val[1]
                          + val[2] * val[2] + val[3] * val[3];
            partial += __shfl_xor(partial, 1, 64);
            partial += __shfl_xor(partial, 2, 64);
            partial += __shfl_xor(partial, 4, 64);
            partial += __shfl_xor(partial, 8, 64);
            if (lane == 0) sqout[p] = partial;
        }
        if (quad == 0) {
            #pragma unroll
            for (int ct = 0; ct < 4; ++ct) {
                int o = ct * 16 + m;
                float vv = val[ct];
                uint_t bits = __float_as_uint(vv);
                oh[(size_t)p * 64 + o] = (ushort_t)(bits >> 16);
                float hif = __uint_as_float(bits & 0xFFFF0000u);
                ol[(size_t)p * 64 + o] = f2bf(vv - hif);
            }
        }
    }
}

// ---------------- final MLP: wave-private, barrier-free; layers 1-3 all MFMA ------
__global__ __launch_bounds__(128, 2) void mlp_kernel(const ushort_t* __restrict__ xh1,
                                                  const ushort_t* __restrict__ xl1,
                                                  const ushort_t* __restrict__ xh2,
                                                  const ushort_t* __restrict__ xl2,
                                                  const ushort_t* __restrict__ xh3,
                                                  const ushort_t* __restrict__ xl3,
                                                  const ushort_t* __restrict__ w1fh,
                                                  const ushort_t* __restrict__ w1fl,
                                                  const ushort_t* __restrict__ w23fh,
                                                  const ushort_t* __restrict__ w23fl,
                                                  const float* __restrict__ mb1,
                                                  const float* __restrict__ mb2,
                                                  const float* __restrict__ mb3,
                                                  const float* __restrict__ mw4, const float* __restrict__ mb4,
                                                  float* __restrict__ out) {
    __shared__ float smem[2][128 * 17];      // 8704 B per wave
    int wave = threadIdx.x >> 6, lane = threadIdx.x & 63;
    float* h1w = smem[wave];                 // [128][17]  [channel][point]
    float* h2w = smem[wave];                 // [64][17]   overlays h1 (written after all h1 reads)
    float* h3w = smem[wave] + 64 * 17;       // [32][17]   overlays h1's upper half
    int m = lane & 15, quad = lane >> 4;
    int pw = blockIdx.x * 32 + wave * 16;    // this wave's 16 points

    const ushort_t* HS[3] = {xh1, xh2, xh3};
    const ushort_t* LS[3] = {xl1, xl2, xl3};
    bf16x8_t Ah[6], Al[6];
    #pragma unroll
    for (int ks = 0; ks < 6; ++ks) {
        size_t aoff = (size_t)(pw + m) * 64 + (ks & 1) * 32 + quad * 8;
        Ah[ks] = *(const bf16x8_t*)(HS[ks >> 1] + aoff);
        Al[ks] = *(const bf16x8_t*)(LS[ks >> 1] + aoff);
    }
    // ---- layer 1: [16 x 192] @ [192 x 128], MFMA ----
    f32x4_t acc1[8];
    #pragma unroll
    for (int nt = 0; nt < 8; ++nt) acc1[nt] = (f32x4_t){0.f, 0.f, 0.f, 0.f};
    #pragma unroll
    for (int ks = 0; ks < 6; ++ks) {
        bf16x8_t Bh[8], Bl[8];
        #pragma unroll
        for (int nt = 0; nt < 8; ++nt) {
            size_t boff = (size_t)(nt * 6 + ks) * 512 + lane * 8;
            Bh[nt] = *(const bf16x8_t*)(w1fh + boff);
            Bl[nt] = *(const bf16x8_t*)(w1fl + boff);
        }
        #pragma unroll
        for (int nt = 0; nt < 8; ++nt) {
            acc1[nt] = __builtin_amdgcn_mfma_f32_16x16x32_bf16(Ah[ks], Bh[nt], acc1[nt], 0, 0, 0);
            acc1[nt] = __builtin_amdgcn_mfma_f32_16x16x32_bf16(Ah[ks], Bl[nt], acc1[nt], 0, 0, 0);
            acc1[nt] = __builtin_amdgcn_mfma_f32_16x16x32_bf16(Al[ks], Bh[nt], acc1[nt], 0, 0, 0);
        }
    }
    #pragma unroll
    for (int nt = 0; nt < 8; ++nt) {
        float bb = mb1[nt * 16 + m];
        float4 w;
        w.x = fmaxf(acc1[nt][0] + bb, 0.f);
        w.y = fmaxf(acc1[nt][1] + bb, 0.f);
        w.z = fmaxf(acc1[nt][2] + bb, 0.f);
        w.w = fmaxf(acc1[nt][3] + bb, 0.f);
        *(float4*)&h1w[(nt * 16 + m) * 17 + quad * 4] = w;
    }
    // ---- layer 2: [16 x 128] @ [128 x 64], MFMA; A-frags from LDS hi/lo split ----
    f32x4_t acc2[4];
    #pragma unroll
    for (int nt = 0; nt < 4; ++nt) acc2[nt] = (f32x4_t){0.f, 0.f, 0.f, 0.f};
    #pragma unroll
    for (int ks = 0; ks < 4; ++ks) {
        union { ushort_t s[8]; bf16x8_t v8; } H, L;
        #pragma unroll
        for (int e = 0; e < 8; ++e) {
            float g = h1w[(ks * 32 + quad * 8 + e) * 17 + m];
            uint_t bits = __float_as_uint(g);
            H.s[e] = (ushort_t)(bits >> 16);
            float hif = __uint_as_float(bits & 0xFFFF0000u);
            L.s[e] = f2bf(g - hif);
        }
        bf16x8_t A2h = H.v8, A2l = L.v8;
        #pragma unroll
        for (int nt = 0; nt < 4; ++nt) {
            size_t boff = (size_t)(nt * 4 + ks) * 512 + lane * 8;
            bf16x8_t Bh = *(const bf16x8_t*)(w23fh + boff);
            bf16x8_t Bl = *(const bf16x8_t*)(w23fl + boff);
            acc2[nt] = __builtin_amdgcn_mfma_f32_16x16x32_bf16(A2h, Bh, acc2[nt], 0, 0, 0);
            acc2[nt] = __builtin_amdgcn_mfma_f32_16x16x32_bf16(A2h, Bl, acc2[nt], 0, 0, 0);
            acc2[nt] = __builtin_amdgcn_mfma_f32_16x16x32_bf16(A2l, Bh, acc2[nt], 0, 0, 0);
        }
    }
    #pragma unroll
    for (int nt = 0; nt < 4; ++nt) {
        float bb = mb2[nt * 16 + m];
        float4 w;
        w.x = fmaxf(acc2[nt][0] + bb, 0.f);
        w.y = fmaxf(acc2[nt][1] + bb, 0.f);
        w.z = fmaxf(acc2[nt][2] + bb, 0.f);
        w.w = fmaxf(acc2[nt][3] + bb, 0.f);
        *(float4*)&h2w[(nt * 16 + m) * 17 + quad * 4] = w;
    }
    // ---- layer 3: [16 x 64] @ [64 x 32], MFMA ----
    f32x4_t acc3[2];
    #pragma unroll
    for (int nt = 0; nt < 2; ++nt) acc3[nt] = (f32x4_t){0.f, 0.f, 0.f, 0.f};
    #pragma unroll
    for (int ks = 0; ks < 2; ++ks) {
        union { ushort_t s[8]; bf16x8_t v8; } H, L;
        #pragma unroll
        for (int e = 0; e < 8; ++e) {
            float g = h2w[(ks * 32 + quad * 8 + e) * 17 + m];
            uint_t bits = __float_as_uint(g);
            H.s[e] = (ushort_t)(bits >> 16);
            float hif = __uint_as_float(bits & 0xFFFF0000u);
            L.s[e] = f2bf(g - hif);
        }
        bf16x8_t A3h = H.v8, A3l = L.v8;
        #pragma unroll
        for (int nt = 0; nt < 2; ++nt) {
            size_t boff = (size_t)(8192 + (nt * 2 + ks) * 512) + lane * 8;
            bf16x8_t Bh = *(const bf16x8_t*)(w23fh + boff);
            bf16x8_t Bl = *(const bf16x8_t*)(w23fl + boff);
            acc3[nt] = __builtin_amdgcn_mfma_f32_16x16x32_bf16(A3h, Bh, acc3[nt], 0, 0, 0);
            acc3[nt] = __builtin_amdgcn_mfma_f32_16x16x32_bf16(A3h, Bl, acc3[nt], 0, 0, 0);
            acc3[nt] = __builtin_amdgcn_mfma_f32_16x16x32_bf16(A3l, Bh, acc3[nt], 0, 0, 0);
        }
    }
    #pragma unroll
    for (int nt = 0; nt < 2; ++nt) {
        float bb = mb3[nt * 16 + m];
        float4 w;
        w.x = fmaxf(acc3[nt][0] + bb, 0.f);
        w.y = fmaxf(acc3[nt][1] + bb, 0.f);
        w.z = fmaxf(acc3[nt][2] + bb, 0.f);
        w.w = fmaxf(acc3[nt][3] + bb, 0.f);
        *(float4*)&h3w[(nt * 16 + m) * 17 + quad * 4] = w;
    }
    // ---- layer 4 + log_softmax (tiny): lane<16 = point ----
    if (lane < 16) {
        float z0 = mb4[0], z1 = mb4[1];
        #pragma unroll 8
        for (int c = 0; c < 32; ++c) {
            float h = h3w[c * 17 + lane];
            z0 = fmaf(h, mw4[c * 2 + 0], z0);
            z1 = fmaf(h, mw4[c * 2 + 1], z1);
        }
        float mx = fmaxf(z0, z1);
        float ls = mx + logf(expf(z0 - mx) + expf(z1 - mx));
        float2 o; o.x = z0 - ls; o.y = z1 - ls;
        *(float2*)&out[(size_t)(pw + lane) * 2] = o;
    }
}

extern "C" void kernel_launch(void* const* d_in, const int* in_sizes, int n_in,
                              void* d_out, int out_size, void* d_ws, size_t ws_size,
                              hipStream_t stream) {
    const float* x0   = (const float*)d_in[0];
    const float* c1w1 = (const float*)d_in[1];  const float* c1b1 = (const float*)d_in[2];
    const float* c1w2 = (const float*)d_in[3];  const float* c1b2 = (const float*)d_in[4];
    const float* c2w1 = (const float*)d_in[5];  const float* c2b1 = (const float*)d_in[6];
    const float* c2w2 = (const float*)d_in[7];  const float* c2b2 = (const float*)d_in[8];
    const float* c3w1 = (const float*)d_in[9];  const float* c3b1 = (const float*)d_in[10];
    const float* c3w2 = (const float*)d_in[11]; const float* c3b2 = (const float*)d_in[12];
    const float* mw1  = (const float*)d_in[13]; const float* mb1  = (const float*)d_in[14];
    const float* mw2  = (const float*)d_in[15]; const float* mb2  = (const float*)d_in[16];
    const float* mw3  = (const float*)d_in[17]; const float* mb3  = (const float*)d_in[18];
    const float* mw4  = (const float*)d_in[19]; const float* mb4  = (const float*)d_in[20];

    float* ws = (float*)d_ws;
    const size_t NF = (size_t)NPOINTS * 64;
    float* u  = ws;
    float* v  = u + NF;
    float* sq = v + NF;
    int*  idx = (int*)(sq + NPOINTS);
    ushort_t* xh1 = (ushort_t*)(idx + (size_t)NPOINTS * KNB);
    ushort_t* xl1 = xh1 + NF;
    ushort_t* xh2 = xl1 + NF;
    ushort_t* xl2 = xh2 + NF;
    ushort_t* xh3 = xl2 + NF;
    ushort_t* xl3 = xh3 + NF;
    ushort_t* w1fh = xl3 + NF;
    ushort_t* w1fl = w1fh + 128 * 192;
    ushort_t* w2fh = w1fl + 128 * 192;       // 3 layers x 4096
    ushort_t* w2fl = w2fh + 3 * 4096;
    float* wuv = (float*)(w2fl + 3 * 4096);  // 3 x 1024 fp32 layer-1 uv consts
    ushort_t* wuvfh = (ushort_t*)(wuv + 3072);   // 2 layers x 8192
    ushort_t* wuvfl = wuvfh + 2 * 8192;
    ushort_t* w23fh = wuvfl + 2 * 8192;      // mlp w2 frags (8192) + w3 frags (2048)
    ushort_t* w23fl = w23fh + 10240;
    float* out = (float*)d_out;

    // ---- fused weight prep + layer-1 sort-knn (independent; overlapped) ----
    prep_kernel<<<313, 256, 0, stream>>>(mw1, c1w2, c2w2, c3w2, c1w1, c1b1,
                                         c2w1, c3w1, mw2, mw3,
                                         w1fh, w1fl, w2fh, w2fl,
                                         wuv, wuvfh, wuvfl, w23fh, w23fl,
                                         x0, idx);
    // ---- layer 1 (C_in = 1): uv-free edge ----
    edge1_mfma_kernel<<<NB * 64, 256, 0, stream>>>(
        x0, idx, w2fh, w2fl, wuv, c1b2, xh1, xl1, sq);
    // ---- layer 2: FUSED knn+uv (sequential in-block) + edge ----
    knnuv_kernel<<<NB * 16, 256, 0, stream>>>(xh1, xl1, sq, idx,
                                              wuvfh, wuvfl, c2b1, u, v);
    edge_mfma_kernel<true><<<NPOINTS / 16, 256, 0, stream>>>(
        u, v, idx, w2fh + 4096, w2fl + 4096, c2b2, xh2, xl2, sq);
    // ---- layer 3 ----
    knnuv_kernel<<<NB * 16, 256, 0, stream>>>(xh2, xl2, sq, idx,
                                              wuvfh + 8192, wuvfl + 8192, c3b1, u, v);
    edge_mfma_kernel<false><<<NPOINTS / 16, 256, 0, stream>>>(
        u, v, idx, w2fh + 8192, w2fl + 8192, c3b2, xh3, xl3, nullptr);
    // ---- final MLP + log_softmax ----
    mlp_kernel<<<NPOINTS / 32, 128, 0, stream>>>(xh1, xl1, xh2, xl2, xh3, xl3,
                                                 w1fh, w1fl, w23fh, w23fl,
                                                 mb1, mb2, mb3, mw4, mb4, out);
}